// Round 1
// baseline (658.739 us; speedup 1.0000x reference)
//
#include <hip/hip_runtime.h>

// CRF forward (partition function), B=512, T=512, L=102.
// One block per batch element; 128 threads (2 waves). Thread j owns output
// state j and keeps exp(trans[j,:] - rowmax[j]) in registers (k-loop fully
// unrolled). Per step: P[k] = exp(alpha[k]-am) lives in LDS; dot in linear
// domain; alpha'[j] = logit + log(dot) + am + rowmax[j].

#define CRF_L 102
#define CRF_LP 104        // padded to multiple of 4 for float4 LDS reads
#define CRF_START 100
#define CRF_STOP 101
#define NEG_BIG (-1.0e30f)

__launch_bounds__(128, 1)
__global__ void crf_forward_kernel(const float* __restrict__ logits,
                                   const float* __restrict__ trans,
                                   const int* __restrict__ lens,
                                   float* __restrict__ out,
                                   int B, int T) {
    const int b    = blockIdx.x;
    const int tid  = threadIdx.x;
    const int lane = tid & 63;
    const int wid  = tid >> 6;
    const int j    = tid;
    const bool active = (tid < CRF_L);

    __shared__ __align__(16) float P[CRF_LP];
    __shared__ float red[2];
    __shared__ float sred[2];

    // ---- Preload exp(trans[j,:] - rowmax[j]) into registers ----
    float m[CRF_LP];
    float rowmax = NEG_BIG;
    if (active) {
        #pragma unroll
        for (int k = 0; k < CRF_L; ++k) {
            m[k] = trans[j * CRF_L + k];
            rowmax = fmaxf(rowmax, m[k]);
        }
        #pragma unroll
        for (int k = 0; k < CRF_L; ++k) {
            m[k] = __expf(m[k] - rowmax);
        }
    } else {
        #pragma unroll
        for (int k = 0; k < CRF_L; ++k) m[k] = 0.0f;
    }
    m[CRF_L]     = 0.0f;
    m[CRF_L + 1] = 0.0f;

    // ---- Init alpha / P / am ----
    float alpha_j;
    if (active) alpha_j = (j == CRF_START) ? 0.0f : -10000.0f;
    else        alpha_j = NEG_BIG;

    if (tid < CRF_LP) P[tid] = (tid == CRF_START) ? 1.0f : 0.0f;
    float am = 0.0f;   // max over alpha (start state is 0)
    __syncthreads();

    const int len = min(lens[b], T);
    const float* lg = logits + (size_t)b * (size_t)T * (size_t)CRF_L;

    for (int t = 0; t < len; ++t) {
        float logit = active ? lg[(size_t)t * CRF_L + j] : 0.0f;

        // dot(Mexp[j,:], P[:]) in fp32, 4 accumulators, float4 LDS broadcast
        float4 a4 = {0.0f, 0.0f, 0.0f, 0.0f};
        const float4* P4 = reinterpret_cast<const float4*>(P);
        #pragma unroll
        for (int kk = 0; kk < CRF_LP / 4; ++kk) {
            float4 p = P4[kk];
            a4.x = fmaf(m[4 * kk + 0], p.x, a4.x);
            a4.y = fmaf(m[4 * kk + 1], p.y, a4.y);
            a4.z = fmaf(m[4 * kk + 2], p.z, a4.z);
            a4.w = fmaf(m[4 * kk + 3], p.w, a4.w);
        }
        float acc = (a4.x + a4.y) + (a4.z + a4.w);

        if (active) alpha_j = logit + __logf(acc) + am + rowmax;

        // block max of alpha (inactive threads hold NEG_BIG)
        float v = alpha_j;
        #pragma unroll
        for (int off = 32; off > 0; off >>= 1)
            v = fmaxf(v, __shfl_xor(v, off, 64));
        if (lane == 0) red[wid] = v;
        __syncthreads();   // also guarantees all dots done before P rewrite
        float amn = fmaxf(red[0], red[1]);

        if (active) P[j] = __expf(alpha_j - amn);
        am = amn;
        __syncthreads();
    }

    // ---- Epilogue: alpha += trans[STOP, :]; out[b] = LSE_j(alpha) ----
    if (active) alpha_j += trans[CRF_STOP * CRF_L + j];

    float v = alpha_j;
    #pragma unroll
    for (int off = 32; off > 0; off >>= 1)
        v = fmaxf(v, __shfl_xor(v, off, 64));
    if (lane == 0) red[wid] = v;
    __syncthreads();
    float fm = fmaxf(red[0], red[1]);

    float e = active ? __expf(alpha_j - fm) : 0.0f;
    #pragma unroll
    for (int off = 32; off > 0; off >>= 1)
        e += __shfl_xor(e, off, 64);
    if (lane == 0) sred[wid] = e;
    __syncthreads();

    if (tid == 0) out[b] = fm + __logf(sred[0] + sred[1]);
}

extern "C" void kernel_launch(void* const* d_in, const int* in_sizes, int n_in,
                              void* d_out, int out_size, void* d_ws, size_t ws_size,
                              hipStream_t stream) {
    const float* logits = (const float*)d_in[0];   // [B, T, L] fp32
    const float* trans  = (const float*)d_in[1];   // [L, L] fp32
    const int*   lens   = (const int*)d_in[2];     // [B] int32
    float* out = (float*)d_out;                    // [B] fp32

    const int B = 512;
    const int T = 512;

    crf_forward_kernel<<<dim3(B), dim3(128), 0, stream>>>(
        logits, trans, lens, out, B, T);
}

// Round 2
// 580.323 us; speedup vs baseline: 1.1351x; 1.1351x over previous
//
#include <hip/hip_runtime.h>

// CRF forward (partition fn), B=512, T=512, L=102 (start=100, stop=101).
// One block = ONE wave (64 threads) per batch element; lane owns rows
// 2*lane, 2*lane+1 (rows padded to 128; lanes 51..63 idle-but-lockstep).
// Linear-domain recurrence with per-step uniform shift:
//   P[k] = exp(alpha[k] - scP)   (LDS, 104 floats padded)
//   dot_j = sum_k exp(trans[j,k]-rowmax[j]) * P[k]   (Mexp in VGPRs)
//   g_j   = logit + rowmax_j + log(dot_j);  alpha_j = g_j + base
// DELAYED MAX: the shift applied to P is last step's max-of-g (uniform,
// exactly accounted in scP/base) so the 6-shuffle reduction is off the
// critical path. No __syncthreads anywhere in the step loop.

#define CRF_L 102
#define CRF_KP 104        // k padded to multiple of 4
#define CRF_START 100
#define CRF_STOP 101
#define NEG_BIG (-1.0e30f)

__launch_bounds__(64, 1)
__global__ void crf_forward_kernel(const float* __restrict__ logits,
                                   const float* __restrict__ trans,
                                   const int* __restrict__ lens,
                                   float* __restrict__ out,
                                   int B, int T) {
    const int b    = blockIdx.x;
    const int lane = threadIdx.x;      // 0..63
    const int r0   = 2 * lane;
    const int r1   = 2 * lane + 1;
    const bool valid = (lane < 51);    // rows 0..101 live on lanes 0..50

    __shared__ __align__(16) float P[CRF_KP];

    // ---- Preload Mexp rows (2 per lane) into registers ----
    float m0[CRF_KP], m1[CRF_KP];
    float rmax0 = NEG_BIG, rmax1 = NEG_BIG;
    if (valid) {
        #pragma unroll
        for (int k = 0; k < CRF_L; ++k) {
            m0[k] = trans[r0 * CRF_L + k];
            m1[k] = trans[r1 * CRF_L + k];
            rmax0 = fmaxf(rmax0, m0[k]);
            rmax1 = fmaxf(rmax1, m1[k]);
        }
        #pragma unroll
        for (int k = 0; k < CRF_L; ++k) {
            m0[k] = __expf(m0[k] - rmax0);
            m1[k] = __expf(m1[k] - rmax1);
        }
    } else {
        #pragma unroll
        for (int k = 0; k < CRF_L; ++k) { m0[k] = 0.f; m1[k] = 0.f; }
        rmax0 = 0.f; rmax1 = 0.f;
    }
    #pragma unroll
    for (int k = CRF_L; k < CRF_KP; ++k) { m0[k] = 0.f; m1[k] = 0.f; }

    // ---- Init state ----
    // alpha = g + base;   P[k] = exp(alpha_k - scP);  Rprev = max_j g_j (stale by 1)
    float g0 = valid ? ((r0 == CRF_START) ? 0.f : -10000.f) : NEG_BIG;
    float g1 = valid ? ((r1 == CRF_START) ? 0.f : -10000.f) : NEG_BIG;
    float base = 0.f, scP = 0.f, Rprev = 0.f;

    if (lane < CRF_KP / 2) {
        // P init = exp(alpha0 - 0): 1 at START, ~0 elsewhere (exp(-10000)->0)
        float p0 = (2 * lane == CRF_START) ? 1.f : 0.f;
        float p1 = (2 * lane + 1 == CRF_START) ? 1.f : 0.f;
        *reinterpret_cast<float2*>(&P[2 * lane]) = make_float2(p0, p1);
    }
    __builtin_amdgcn_wave_barrier();

    const int len = min(lens[b], T);
    const float* lg = logits + (size_t)b * (size_t)T * (size_t)CRF_L;
    const int loff = valid ? r0 : 0;   // lanes >=51 load a safe dummy addr

    // depth-2 prefetch pipeline of logit pairs
    float2 lgA = *reinterpret_cast<const float2*>(lg + (size_t)min(0, T - 1) * CRF_L + loff);
    float2 lgB = *reinterpret_cast<const float2*>(lg + (size_t)min(1, T - 1) * CRF_L + loff);

    for (int t = 0; t < len; ++t) {
        float2 lo = lgA;
        lgA = lgB;
        int pf = min(t + 2, T - 1);
        lgB = *reinterpret_cast<const float2*>(lg + (size_t)pf * CRF_L + loff);

        // ---- dot over k (both rows), float4 LDS broadcast reads ----
        float4 a0 = {0.f, 0.f, 0.f, 0.f};
        float4 a1 = {0.f, 0.f, 0.f, 0.f};
        const float4* P4 = reinterpret_cast<const float4*>(P);
        #pragma unroll
        for (int kk = 0; kk < CRF_KP / 4; ++kk) {
            float4 p = P4[kk];
            a0.x = fmaf(m0[4 * kk + 0], p.x, a0.x);
            a0.y = fmaf(m0[4 * kk + 1], p.y, a0.y);
            a0.z = fmaf(m0[4 * kk + 2], p.z, a0.z);
            a0.w = fmaf(m0[4 * kk + 3], p.w, a0.w);
            a1.x = fmaf(m1[4 * kk + 0], p.x, a1.x);
            a1.y = fmaf(m1[4 * kk + 1], p.y, a1.y);
            a1.z = fmaf(m1[4 * kk + 2], p.z, a1.z);
            a1.w = fmaf(m1[4 * kk + 3], p.w, a1.w);
        }
        float dot0 = (a0.x + a0.y) + (a0.z + a0.w);
        float dot1 = (a1.x + a1.y) + (a1.z + a1.w);

        float ng0 = lo.x + rmax0 + __logf(dot0);
        float ng1 = lo.y + rmax1 + __logf(dot1);
        g0 = valid ? ng0 : NEG_BIG;
        g1 = valid ? ng1 : NEG_BIG;

        // ---- rescale with DELAYED max (Rprev from previous step) ----
        base = scP;            // alpha = g + base
        scP  = scP + Rprev;    // scale now embedded in P
        float p0 = valid ? __expf(g0 - Rprev) : 0.f;
        float p1 = valid ? __expf(g1 - Rprev) : 0.f;
        __builtin_amdgcn_wave_barrier();   // all dot reads done (lockstep wave)
        *reinterpret_cast<float2*>(&P[r0 < CRF_KP ? r0 : 0]) =
            (r0 < CRF_KP) ? make_float2(p0, p1) : *reinterpret_cast<float2*>(&P[0]);
        __builtin_amdgcn_wave_barrier();

        // ---- off-critical-path max reduction for NEXT step ----
        float v = fmaxf(g0, g1);
        #pragma unroll
        for (int off = 32; off > 0; off >>= 1)
            v = fmaxf(v, __shfl_xor(v, off, 64));
        Rprev = v;
    }

    // ---- Epilogue: alpha += trans[STOP,:]; out[b] = LSE ----
    float t0 = valid ? trans[CRF_STOP * CRF_L + r0] : 0.f;
    float t1 = valid ? trans[CRF_STOP * CRF_L + r1] : 0.f;
    float av0 = valid ? (g0 + base + t0) : NEG_BIG;
    float av1 = valid ? (g1 + base + t1) : NEG_BIG;

    float vmax = fmaxf(av0, av1);
    #pragma unroll
    for (int off = 32; off > 0; off >>= 1)
        vmax = fmaxf(vmax, __shfl_xor(vmax, off, 64));

    float e = valid ? (__expf(av0 - vmax) + __expf(av1 - vmax)) : 0.f;
    #pragma unroll
    for (int off = 32; off > 0; off >>= 1)
        e += __shfl_xor(e, off, 64);

    if (lane == 0) out[b] = vmax + __logf(e);
}

extern "C" void kernel_launch(void* const* d_in, const int* in_sizes, int n_in,
                              void* d_out, int out_size, void* d_ws, size_t ws_size,
                              hipStream_t stream) {
    const float* logits = (const float*)d_in[0];   // [B, T, L] fp32
    const float* trans  = (const float*)d_in[1];   // [L, L] fp32
    const int*   lens   = (const int*)d_in[2];     // [B] int32
    float* out = (float*)d_out;                    // [B] fp32

    const int B = 512;
    const int T = 512;

    crf_forward_kernel<<<dim3(B), dim3(64), 0, stream>>>(
        logits, trans, lens, out, B, T);
}

// Round 3
// 565.497 us; speedup vs baseline: 1.1649x; 1.0262x over previous
//
#include <hip/hip_runtime.h>

// CRF forward (partition fn), B=512, T=512, L=102 (start=100, stop=101).
// One block = ONE wave (64 threads) per batch element; lane owns rows
// 2*lane, 2*lane+1. Mexp rows live in VGPRs -- amdgpu_waves_per_eu(1,1)
// forces the allocator to give us ~256 VGPRs instead of spilling to
// scratch (R2's 27 GB FETCH_SIZE was spill traffic).
// Linear-domain recurrence with DELAYED uniform shift (prev step's max),
// so the shuffle reduction is off the critical path. No __syncthreads.

#define CRF_L 102
#define CRF_KP 104        // k padded to multiple of 4
#define CRF_START 100
#define CRF_STOP 101
#define NEG_BIG (-1.0e30f)

__attribute__((amdgpu_waves_per_eu(1, 1)))
__launch_bounds__(64)
__global__ void crf_forward_kernel(const float* __restrict__ logits,
                                   const float* __restrict__ trans,
                                   const int* __restrict__ lens,
                                   float* __restrict__ out,
                                   int B, int T) {
    const int b    = blockIdx.x;
    const int lane = threadIdx.x;      // 0..63
    const int r0   = 2 * lane;
    const int r1   = 2 * lane + 1;
    const bool valid = (lane < 51);    // rows 0..101 live on lanes 0..50

    __shared__ __align__(16) float P[CRF_KP];

    // ---- Preload Mexp rows (2 per lane) into registers ----
    float m0[CRF_KP], m1[CRF_KP];
    float rmax0 = NEG_BIG, rmax1 = NEG_BIG;
    if (valid) {
        #pragma unroll
        for (int k = 0; k < CRF_L; ++k) {
            m0[k] = trans[r0 * CRF_L + k];
            m1[k] = trans[r1 * CRF_L + k];
            rmax0 = fmaxf(rmax0, m0[k]);
            rmax1 = fmaxf(rmax1, m1[k]);
        }
        #pragma unroll
        for (int k = 0; k < CRF_L; ++k) {
            m0[k] = __expf(m0[k] - rmax0);
            m1[k] = __expf(m1[k] - rmax1);
        }
    } else {
        #pragma unroll
        for (int k = 0; k < CRF_L; ++k) { m0[k] = 0.f; m1[k] = 0.f; }
        rmax0 = 0.f; rmax1 = 0.f;
    }
    #pragma unroll
    for (int k = CRF_L; k < CRF_KP; ++k) { m0[k] = 0.f; m1[k] = 0.f; }

    // ---- Init state ----
    // alpha = g + base;  P[k] = exp(alpha_k - scP);  Rprev = stale max of g
    float g0 = valid ? ((r0 == CRF_START) ? 0.f : -10000.f) : NEG_BIG;
    float g1 = valid ? ((r1 == CRF_START) ? 0.f : -10000.f) : NEG_BIG;
    float base = 0.f, scP = 0.f, Rprev = 0.f;

    if (lane < CRF_KP / 2) {
        float p0 = (2 * lane == CRF_START) ? 1.f : 0.f;
        float p1 = (2 * lane + 1 == CRF_START) ? 1.f : 0.f;
        *reinterpret_cast<float2*>(&P[2 * lane]) = make_float2(p0, p1);
    }
    __builtin_amdgcn_wave_barrier();

    const int len = min(lens[b], T);
    const float* lg = logits + (size_t)b * (size_t)T * (size_t)CRF_L;
    const int loff = valid ? r0 : 0;   // lanes >=51 load a safe dummy addr

    // depth-2 prefetch pipeline of logit pairs
    float2 lgA = *reinterpret_cast<const float2*>(lg + loff);
    float2 lgB = *reinterpret_cast<const float2*>(lg + (size_t)min(1, T - 1) * CRF_L + loff);

    for (int t = 0; t < len; ++t) {
        float2 lo = lgA;
        lgA = lgB;
        int pf = min(t + 2, T - 1);
        lgB = *reinterpret_cast<const float2*>(lg + (size_t)pf * CRF_L + loff);

        // ---- dot over k (both rows), float4 LDS broadcast reads ----
        float4 a0 = {0.f, 0.f, 0.f, 0.f};
        float4 a1 = {0.f, 0.f, 0.f, 0.f};
        const float4* P4 = reinterpret_cast<const float4*>(P);
        #pragma unroll
        for (int kk = 0; kk < CRF_KP / 4; ++kk) {
            float4 p = P4[kk];
            a0.x = fmaf(m0[4 * kk + 0], p.x, a0.x);
            a0.y = fmaf(m0[4 * kk + 1], p.y, a0.y);
            a0.z = fmaf(m0[4 * kk + 2], p.z, a0.z);
            a0.w = fmaf(m0[4 * kk + 3], p.w, a0.w);
            a1.x = fmaf(m1[4 * kk + 0], p.x, a1.x);
            a1.y = fmaf(m1[4 * kk + 1], p.y, a1.y);
            a1.z = fmaf(m1[4 * kk + 2], p.z, a1.z);
            a1.w = fmaf(m1[4 * kk + 3], p.w, a1.w);
        }
        float dot0 = (a0.x + a0.y) + (a0.z + a0.w);
        float dot1 = (a1.x + a1.y) + (a1.z + a1.w);

        float ng0 = lo.x + rmax0 + __logf(dot0);
        float ng1 = lo.y + rmax1 + __logf(dot1);
        g0 = valid ? ng0 : NEG_BIG;
        g1 = valid ? ng1 : NEG_BIG;

        // ---- rescale with DELAYED max (Rprev from previous step) ----
        base = scP;            // alpha = g + base
        scP  = scP + Rprev;    // scale now embedded in P
        float p0 = valid ? __expf(g0 - Rprev) : 0.f;
        float p1 = valid ? __expf(g1 - Rprev) : 0.f;
        __builtin_amdgcn_wave_barrier();   // all dot reads done (lockstep wave)
        if (r0 < CRF_KP) {                 // lanes 0..51 store; no race
            *reinterpret_cast<float2*>(&P[r0]) = make_float2(p0, p1);
        }
        __builtin_amdgcn_wave_barrier();

        // ---- off-critical-path max reduction for NEXT step ----
        float v = fmaxf(g0, g1);
        #pragma unroll
        for (int off = 32; off > 0; off >>= 1)
            v = fmaxf(v, __shfl_xor(v, off, 64));
        Rprev = v;
    }

    // ---- Epilogue: alpha += trans[STOP,:]; out[b] = LSE ----
    float t0 = valid ? trans[CRF_STOP * CRF_L + r0] : 0.f;
    float t1 = valid ? trans[CRF_STOP * CRF_L + r1] : 0.f;
    float av0 = valid ? (g0 + base + t0) : NEG_BIG;
    float av1 = valid ? (g1 + base + t1) : NEG_BIG;

    float vmax = fmaxf(av0, av1);
    #pragma unroll
    for (int off = 32; off > 0; off >>= 1)
        vmax = fmaxf(vmax, __shfl_xor(vmax, off, 64));

    float e = valid ? (__expf(av0 - vmax) + __expf(av1 - vmax)) : 0.f;
    #pragma unroll
    for (int off = 32; off > 0; off >>= 1)
        e += __shfl_xor(e, off, 64);

    if (lane == 0) out[b] = vmax + __logf(e);
}

extern "C" void kernel_launch(void* const* d_in, const int* in_sizes, int n_in,
                              void* d_out, int out_size, void* d_ws, size_t ws_size,
                              hipStream_t stream) {
    const float* logits = (const float*)d_in[0];   // [B, T, L] fp32
    const float* trans  = (const float*)d_in[1];   // [L, L] fp32
    const int*   lens   = (const int*)d_in[2];     // [B] int32
    float* out = (float*)d_out;                    // [B] fp32

    const int B = 512;
    const int T = 512;

    crf_forward_kernel<<<dim3(B), dim3(64), 0, stream>>>(
        logits, trans, lens, out, B, T);
}

// Round 4
// 541.672 us; speedup vs baseline: 1.2161x; 1.0440x over previous
//
#include <hip/hip_runtime.h>

// CRF forward (partition fn), B=512, T=512, L=102 (start=100, stop=101).
// One block (2 waves, 128 threads) per batch element; thread tid owns row
// tid (tid<102). The row of Mexp = exp(trans[j,:]-rowmax[j]) lives in 26
// NAMED float4 SSA variables (macro-unrolled) -- no alloca, so it cannot
// be demoted to scratch (R1-R3's 27 GB FETCH_SIZE was scratch re-reads of
// unpromoted local arrays). P[104] fp32 in LDS, read as float4 broadcasts.
// Delayed-max rescale (prev step's max, exactly accounted in scP/base)
// keeps the reduction off the critical path; 2 barriers/step.

#define CRF_L 102
#define CRF_KP 104
#define CRF_START 100
#define CRF_STOP 101
#define NEG_BIG (-1.0e30f)

#define REP26(X) X(0) X(1) X(2) X(3) X(4) X(5) X(6) X(7) X(8) X(9) X(10) \
                 X(11) X(12) X(13) X(14) X(15) X(16) X(17) X(18) X(19) \
                 X(20) X(21) X(22) X(23) X(24) X(25)

__attribute__((amdgpu_waves_per_eu(1)))
__launch_bounds__(128)
__global__ void crf_forward_kernel(const float* __restrict__ logits,
                                   const float* __restrict__ trans,
                                   const int* __restrict__ lens,
                                   float* __restrict__ out,
                                   int B, int T) {
    const int b    = blockIdx.x;
    const int tid  = threadIdx.x;      // 0..127
    const int wid  = tid >> 6;
    const int row  = tid;
    const bool valid = (tid < CRF_L);

    __shared__ __align__(16) float P[CRF_KP];
    __shared__ float wslot[2];
    __shared__ float sslot[2];

    // ---- Mexp row in 26 named float4 registers ----
#define DECL_M(i) float4 m##i;
    REP26(DECL_M)
#undef DECL_M

    const float* trow = trans + (size_t)row * CRF_L;
#define LOAD_M(i) \
    m##i.x = (valid && (4*(i)+0) < CRF_L) ? trow[4*(i)+0] : NEG_BIG; \
    m##i.y = (valid && (4*(i)+1) < CRF_L) ? trow[4*(i)+1] : NEG_BIG; \
    m##i.z = (valid && (4*(i)+2) < CRF_L) ? trow[4*(i)+2] : NEG_BIG; \
    m##i.w = (valid && (4*(i)+3) < CRF_L) ? trow[4*(i)+3] : NEG_BIG;
    REP26(LOAD_M)
#undef LOAD_M

    float rmax = NEG_BIG;
#define MAX_M(i) rmax = fmaxf(rmax, fmaxf(fmaxf(m##i.x, m##i.y), fmaxf(m##i.z, m##i.w)));
    REP26(MAX_M)
#undef MAX_M

#define EXP_M(i) \
    m##i.x = __expf(m##i.x - rmax); m##i.y = __expf(m##i.y - rmax); \
    m##i.z = __expf(m##i.z - rmax); m##i.w = __expf(m##i.w - rmax);
    REP26(EXP_M)
#undef EXP_M
    // invalid threads: rmax=-1e30, m=exp(0)=1 -- harmless, they never write.

    // ---- Init state (delayed-max bookkeeping, validated in R3) ----
    float g    = valid ? ((row == CRF_START) ? 0.f : -10000.f) : NEG_BIG;
    float base = 0.f, scP = 0.f, Rprev = 0.f;

    if (tid < CRF_KP) P[tid] = (tid == CRF_START) ? 1.f : 0.f;
    __syncthreads();

    const int len = min(lens[b], T);
    const float* lg = logits + (size_t)b * (size_t)T * (size_t)CRF_L;
    const int loff = valid ? row : 0;

    // depth-2 logit prefetch (coalesced scalar loads)
    float lgA = lg[loff];
    float lgB = lg[(size_t)min(1, T - 1) * CRF_L + loff];

    const float4* P4 = reinterpret_cast<const float4*>(P);

    for (int t = 0; t < len; ++t) {
        float lo = lgA;
        lgA = lgB;
        int pf = min(t + 2, T - 1);
        lgB = lg[(size_t)pf * CRF_L + loff];

        // ---- dot(Mexp[row,:], P[:]) -- 26 float4 LDS broadcasts ----
        float4 acc = {0.f, 0.f, 0.f, 0.f};
#define FMA_M(i) { float4 p = P4[i]; \
        acc.x = fmaf(m##i.x, p.x, acc.x); acc.y = fmaf(m##i.y, p.y, acc.y); \
        acc.z = fmaf(m##i.z, p.z, acc.z); acc.w = fmaf(m##i.w, p.w, acc.w); }
        REP26(FMA_M)
#undef FMA_M
        float dot = (acc.x + acc.y) + (acc.z + acc.w);

        float ng = lo + rmax + __logf(dot);
        g = valid ? ng : NEG_BIG;

        base = scP;            // alpha = g + base
        scP  = scP + Rprev;    // shift embedded in new P
        float p = __expf(g - Rprev);

        __syncthreads();       // barrier A: all dot reads done before P rewrite
        if (valid) P[tid] = p;

        // off-critical-path max for NEXT step (stale by one)
        float v = g;
        #pragma unroll
        for (int off = 32; off > 0; off >>= 1)
            v = fmaxf(v, __shfl_xor(v, off, 64));
        if ((tid & 63) == 0) wslot[wid] = v;
        __syncthreads();       // barrier B: P + wslot visible
        Rprev = fmaxf(wslot[0], wslot[1]);
    }

    // ---- Epilogue: alpha += trans[STOP,:]; out[b] = LSE ----
    __syncthreads();           // protect wslot reuse across waves
    float tstop = valid ? trans[(size_t)CRF_STOP * CRF_L + row] : 0.f;
    float av = valid ? (g + base + tstop) : NEG_BIG;

    float vmax = av;
    #pragma unroll
    for (int off = 32; off > 0; off >>= 1)
        vmax = fmaxf(vmax, __shfl_xor(vmax, off, 64));
    if ((tid & 63) == 0) wslot[wid] = vmax;
    __syncthreads();
    float fm = fmaxf(wslot[0], wslot[1]);

    float e = valid ? __expf(av - fm) : 0.f;
    #pragma unroll
    for (int off = 32; off > 0; off >>= 1)
        e += __shfl_xor(e, off, 64);
    if ((tid & 63) == 0) sslot[wid] = e;
    __syncthreads();

    if (tid == 0) out[b] = fm + __logf(sslot[0] + sslot[1]);
}

extern "C" void kernel_launch(void* const* d_in, const int* in_sizes, int n_in,
                              void* d_out, int out_size, void* d_ws, size_t ws_size,
                              hipStream_t stream) {
    const float* logits = (const float*)d_in[0];   // [B, T, L] fp32
    const float* trans  = (const float*)d_in[1];   // [L, L] fp32
    const int*   lens   = (const int*)d_in[2];     // [B] int32
    float* out = (float*)d_out;                    // [B] fp32

    const int B = 512;
    const int T = 512;

    crf_forward_kernel<<<dim3(B), dim3(128), 0, stream>>>(
        logits, trans, lens, out, B, T);
}

// Round 6
// 459.520 us; speedup vs baseline: 1.4335x; 1.1788x over previous
//
#include <hip/hip_runtime.h>

// CRF forward (partition fn), B=512, T=512, L=102 (start=100, stop=101).
// One block (2 waves, 128 threads) per batch; thread tid owns row tid.
// Mexp = exp(trans[j,:]-rowmax[j]) in f16: 52 named half2 VGPRs (fits the
// ~128-reg RA budget -- R2-R4's 27 GB FETCH_SIZE was register spill).
// P in f16 LDS, double-buffered -> 1 barrier/step. Dot via v_dot2_f32_f16
// (fp32 accumulate). Stabilized delayed shift: S_{t+1} = maxarg_t + 6 ->
// exp-arg = per-step drift - 6 exactly (frame terms cancel; f16-safe).
// R5 NaN root cause: P[1][102..103] never initialized -> 0 * Inf/NaN
// garbage in fdot2. Fixed: zero both buffers' tails at init + dot floor.

typedef _Float16 half2_t __attribute__((ext_vector_type(2)));

#define CRF_L 102
#define CRF_START 100
#define CRF_STOP 101
#define NEG_BIG (-1.0e30f)
#define DRIFT_ALLOW 6.0f

#define REP13(X) X(0) X(1) X(2) X(3) X(4) X(5) X(6) X(7) X(8) X(9) X(10) X(11) X(12)

#if __has_builtin(__builtin_amdgcn_fdot2)
#define FDOT2(a, b, c) __builtin_amdgcn_fdot2((a), (b), (c), false)
#else
static __device__ __forceinline__ float FDOT2(half2_t a, half2_t b, float c) {
    return fmaf((float)a.x, (float)b.x, fmaf((float)a.y, (float)b.y, c));
}
#endif

__attribute__((amdgpu_waves_per_eu(1, 1)))
__launch_bounds__(128)
__global__ void crf_forward_kernel(const float* __restrict__ logits,
                                   const float* __restrict__ trans,
                                   const int* __restrict__ lens,
                                   float* __restrict__ out,
                                   int B, int T) {
    const int b   = blockIdx.x;
    const int tid = threadIdx.x;      // 0..127
    const int wid = tid >> 6;
    const int row = tid;
    const bool valid = (tid < CRF_L);

    __shared__ __align__(16) _Float16 P[2][104];   // 13 float4 per buffer
    __shared__ float wslot[2][2];
    __shared__ float sred[2];

    // ---- pass 1: rowmax ----
    const float* trow = trans + (size_t)row * CRF_L;
    float rmax = NEG_BIG;
    if (valid) {
        for (int k = 0; k < CRF_L; ++k) rmax = fmaxf(rmax, trow[k]);
    } else {
        rmax = 0.f;
    }

    // ---- pass 2: pack exp(trans - rmax) into 52 named half2 registers ----
#define DECLM(j) half2_t m##j##_0, m##j##_1, m##j##_2, m##j##_3;
    REP13(DECLM)
#undef DECLM

#define PACK1(j, c) { \
    const int k0 = 8 * (j) + 2 * (c); \
    float e0 = (valid && (k0 + 0) < CRF_L) ? __expf(trow[k0 + 0] - rmax) : 0.f; \
    float e1 = (valid && (k0 + 1) < CRF_L) ? __expf(trow[k0 + 1] - rmax) : 0.f; \
    m##j##_##c = (half2_t){(_Float16)e0, (_Float16)e1}; }
#define PACKJ(j) PACK1(j, 0) PACK1(j, 1) PACK1(j, 2) PACK1(j, 3)
    REP13(PACKJ)
#undef PACKJ
#undef PACK1

    // ---- init state ----
    // invariant: alpha = g + base; P[cur] = exp(alpha - (base + Sused));
    // Epend = max over lanes of P[cur]'s exp-argument.
    if (tid < 104) {
        P[0][tid] = (_Float16)((tid == CRF_START) ? 1.f : 0.f);
        if (tid >= CRF_L) P[1][tid] = (_Float16)0.f;   // tail of buffer 1 (R5 NaN fix)
    }
    float g    = valid ? ((row == CRF_START) ? 0.f : -10000.f) : NEG_BIG;
    float base = 0.f, Sused = 0.f, Epend = 0.f;
    __syncthreads();

    const int len = min(lens[b], T);
    const float* lg = logits + (size_t)b * (size_t)T * (size_t)CRF_L;
    const int loff = valid ? row : 0;

    // depth-2 logit prefetch (coalesced)
    float lgA = lg[loff];
    float lgB = lg[(size_t)min(1, T - 1) * CRF_L + loff];

    for (int t = 0; t < len; ++t) {
        float lo = lgA;
        lgA = lgB;
        lgB = lg[(size_t)min(t + 2, T - 1) * CRF_L + loff];

        // ---- dot(Mexp[row,:], P[:]) : 13 float4 LDS broadcasts + 52 dot2 ----
        const float4* P4 = reinterpret_cast<const float4*>(&P[t & 1][0]);
        float a0 = 0.f, a1 = 0.f, a2 = 0.f, a3 = 0.f;
#define DOT(j) { float4 q = P4[j]; \
        a0 = FDOT2(m##j##_0, __builtin_bit_cast(half2_t, q.x), a0); \
        a1 = FDOT2(m##j##_1, __builtin_bit_cast(half2_t, q.y), a1); \
        a2 = FDOT2(m##j##_2, __builtin_bit_cast(half2_t, q.z), a2); \
        a3 = FDOT2(m##j##_3, __builtin_bit_cast(half2_t, q.w), a3); }
        REP13(DOT)
#undef DOT
        float dot = (a0 + a1) + (a2 + a3);
        dot = fmaxf(dot, 1e-37f);         // full-underflow row: finite large-neg log

        float gn = valid ? (lo + rmax + __logf(dot)) : NEG_BIG;
        base += Sused;                    // alpha = gn + base
        float Snew = Epend + DRIFT_ALLOW; // exp-arg max = drift - DRIFT (stable)
        float arg = gn - Snew;
        float pf = __expf(arg);

        if (valid) P[(t + 1) & 1][tid] = (_Float16)pf;

        // off-critical-path: max of exp-args for NEXT step's shift
        float v = arg;
        #pragma unroll
        for (int off = 32; off > 0; off >>= 1)
            v = fmaxf(v, __shfl_xor(v, off, 64));
        if ((tid & 63) == 0) wslot[t & 1][wid] = v;

        g = gn;
        Sused = Snew;
        __syncthreads();                  // P[(t+1)&1] + wslot visible
        Epend = fmaxf(wslot[t & 1][0], wslot[t & 1][1]);
    }

    // ---- epilogue: alpha += trans[STOP,:]; out[b] = LSE ----
    __syncthreads();
    float tstop = valid ? trans[(size_t)CRF_STOP * CRF_L + row] : 0.f;
    float av = valid ? (g + base + tstop) : NEG_BIG;

    float vmax = av;
    #pragma unroll
    for (int off = 32; off > 0; off >>= 1)
        vmax = fmaxf(vmax, __shfl_xor(vmax, off, 64));
    if ((tid & 63) == 0) wslot[0][wid] = vmax;
    __syncthreads();
    float fm = fmaxf(wslot[0][0], wslot[0][1]);

    float e = valid ? __expf(av - fm) : 0.f;
    #pragma unroll
    for (int off = 32; off > 0; off >>= 1)
        e += __shfl_xor(e, off, 64);
    if ((tid & 63) == 0) sred[wid] = e;
    __syncthreads();

    if (tid == 0) out[b] = fm + __logf(sred[0] + sred[1]);
}

extern "C" void kernel_launch(void* const* d_in, const int* in_sizes, int n_in,
                              void* d_out, int out_size, void* d_ws, size_t ws_size,
                              hipStream_t stream) {
    const float* logits = (const float*)d_in[0];   // [B, T, L] fp32
    const float* trans  = (const float*)d_in[1];   // [L, L] fp32
    const int*   lens   = (const int*)d_in[2];     // [B] int32
    float* out = (float*)d_out;                    // [B] fp32

    const int B = 512;
    const int T = 512;

    crf_forward_kernel<<<dim3(B), dim3(128), 0, stream>>>(
        logits, trans, lens, out, B, T);
}